// Round 3
// baseline (710.213 us; speedup 1.0000x reference)
//
#include <hip/hip_runtime.h>
#include <math.h>

// Problem constants (from reference): B=16, T=64, H=32, W=32, C=64
constexpr int Bc = 16, Tc = 64, Hc = 32, Wc = 32, Cc = 64;
constexpr int HWC = Hc * Wc * Cc;              // 65536 = 2^16
constexpr long long NELEM = (long long)Bc * Tc * HWC;  // 67,108,864
constexpr float DECAY_V = 0.8f;
constexpr float VTH_BASE = 0.5f;

// clang ext-vector: __builtin_nontemporal_* accepts these (HIP's float4
// class type is rejected — round-2 compile failure).
typedef float v4f __attribute__((ext_vector_type(4)));

// One thread owns 4 consecutive c-values of one (b,h,w) cell and runs the
// whole T=64 recurrence (16 B/lane, the coalescing sweet spot).
//
// DEEP EXPLICIT PREFETCH: round 1 showed wave count is not the lever
// (16->32 waves/CU: only +4%); effective BW stuck at ~2.3 TB/s of 6.3.
// Theory: each wave had ~1 outstanding load (serial xcur=xnext chain +
// stores interleaved between a prefetch and its consumer force in-order
// vmcnt drains). Here we keep a rotating quad of NAMED v4f registers
// (static indexing only — runtime-indexed arrays spill to scratch), issue
// all 4 next-quad loads at the TOP of each block (before any stores), then
// compute+store the current quad. 4-8 KB of reads in flight per wave.
__global__ __launch_bounds__(256) void alif_fwd_kernel(
    const float* __restrict__ x,             // [B,T,H,W,C]
    const float* __restrict__ hp_base_step,  // scalar
    const float* __restrict__ hp_base_decay, // scalar
    const float* __restrict__ step_w_raw,    // [H,W,C]
    const float* __restrict__ decay_w_raw,   // [H,W,C]
    const float* __restrict__ gamma,         // [H,W,C]
    const float* __restrict__ beta,          // [H,W,C]
    float* __restrict__ spikes,              // [B,T,H,W,C]
    float* __restrict__ volts)               // [B,T,H,W,C]
{
    const int tid = blockIdx.x * blockDim.x + threadIdx.x;  // 0 .. 262143
    const int c4  = tid << 2;              // element index into [B,H,W,C]
    const int b   = c4 >> 16;              // / HWC
    const int hwc = c4 & (HWC - 1);        // % HWC

    const float base_step  = *hp_base_step;   // wave-uniform scalar loads
    const float base_decay = *hp_base_decay;

    const v4f swr = *(const v4f*)(step_w_raw  + hwc);
    const v4f dwr = *(const v4f*)(decay_w_raw + hwc);
    const v4f gm4 = *(const v4f*)(gamma       + hwc);
    const v4f bt4 = *(const v4f*)(beta        + hwc);

    float gm[4]    = {gm4.x, gm4.y, gm4.z, gm4.w};
    float bt[4]    = {bt4.x, bt4.y, bt4.z, bt4.w};
    float swr_a[4] = {swr.x, swr.y, swr.z, swr.w};
    float dwr_a[4] = {dwr.x, dwr.y, dwr.z, dwr.w};

    float step_eff[4], decay_eff[4];
    float v[4]   = {0.f, 0.f, 0.f, 0.f};
    float vth[4] = {0.f, 0.f, 0.f, 0.f};

#pragma unroll
    for (int j = 0; j < 4; ++j) {
        // softplus / sigmoid in double, rounded to f32 -> correctly-rounded
        // f32 param path (matches numpy f32 to within its own exp() ulp).
        float sw = (float)log1p(exp((double)swr_a[j]));
        float dw = (float)(1.0 / (1.0 + exp(-(double)dwr_a[j])));
        step_eff[j]  = base_step * sw;
        decay_eff[j] = base_decay + (1.0f - base_decay) * dw;
    }

    const size_t base = (size_t)b * Tc * HWC + (size_t)hwc;
    const float* xp = x      + base;
    float*       sp = spikes + base;
    float*       vp = volts  + base;

    // one recurrence step + both streaming stores
    auto step = [&](const v4f& xv) {
        float xin[4] = {xv.x, xv.y, xv.z, xv.w};
        float sarr[4], varr[4];
#pragma unroll
        for (int j = 0; j < 4; ++j) {
            float vv      = v[j] * DECAY_V + (xin[j] * gm[j] + bt[j]);
            float vth_eff = VTH_BASE + vth[j];
            float s       = (vv - vth_eff > 0.0f) ? 1.0f : 0.0f;
            varr[j] = vv;                       // voltage BEFORE reset
            v[j]    = vv - vth_eff * s;         // soft reset
            vth[j]  = vth[j] * decay_eff[j] + s * step_eff[j];
            sarr[j] = s;
        }
        v4f so = {sarr[0], sarr[1], sarr[2], sarr[3]};
        v4f vo = {varr[0], varr[1], varr[2], varr[3]};
        __builtin_nontemporal_store(so, (v4f*)sp);
        __builtin_nontemporal_store(vo, (v4f*)vp);
        sp += HWC; vp += HWC;
    };

#define LDX(off) __builtin_nontemporal_load((const v4f*)(xp + (size_t)(off) * HWC))

    // preload quad 0 (t = 0..3)
    v4f xa = LDX(0), xb = LDX(1), xc = LDX(2), xd = LDX(3);
    xp += 4 * (size_t)HWC;

    // 15 pipelined quads: issue next-quad loads FIRST, then compute+store
    // the current quad, then rotate. No clamps, no branches in the body.
    for (int k = 0; k < 15; ++k) {
        v4f na = LDX(0), nb = LDX(1), nc = LDX(2), nd = LDX(3);
        xp += 4 * (size_t)HWC;
        step(xa); step(xb); step(xc); step(xd);
        xa = na; xb = nb; xc = nc; xd = nd;
    }
    // tail quad (t = 60..63), no prefetch
    step(xa); step(xb); step(xc); step(xd);

#undef LDX
}

extern "C" void kernel_launch(void* const* d_in, const int* in_sizes, int n_in,
                              void* d_out, int out_size, void* d_ws, size_t ws_size,
                              hipStream_t stream) {
    // Input order per setup_inputs():
    // 0: x, 1: hp_alpha (unused in fwd), 2: hp_base_step, 3: hp_base_decay,
    // 4: step_w_raw, 5: decay_w_raw, 6: gamma, 7: beta
    const float* x             = (const float*)d_in[0];
    const float* hp_base_step  = (const float*)d_in[2];
    const float* hp_base_decay = (const float*)d_in[3];
    const float* step_w_raw    = (const float*)d_in[4];
    const float* decay_w_raw   = (const float*)d_in[5];
    const float* gamma         = (const float*)d_in[6];
    const float* beta          = (const float*)d_in[7];

    float* spikes = (float*)d_out;           // output 0: [B,T,H,W,C]
    float* volts  = spikes + NELEM;          // output 1: [B,T,H,W,C]

    const int threads = 256;
    const int total   = Bc * HWC / 4;        // 262,144 threads
    const int blocks  = total / threads;     // 1024 blocks -> 4 blocks/CU

    alif_fwd_kernel<<<blocks, threads, 0, stream>>>(
        x, hp_base_step, hp_base_decay, step_w_raw, decay_w_raw,
        gamma, beta, spikes, volts);
}